// Round 12
// baseline (3250.676 us; speedup 1.0000x reference)
//
#include <hip/hip_runtime.h>

// ---------------------------------------------------------------------------
// TypeNet: 3 branches x (BN1 -> flattened LSTM (2048 steps) -> BN2 -> LSTM (2048 steps))
// H = 128, gates = 512. Round 12: matvec via v_fma_mix_f32 — f16 sources
// (weights half2: 64 VGPRs, h f16 in LDS) with f32 accumulators at full f32
// VALU rate. Fixes R11's AGPR spill (128 f32 weight regs -> v_accvgpr_read
// per FMA) while keeping R10's full-rate math. LLVM forms fma_mix from
// fmaf((float)f16, (float)f16, acc). Rest = R8 skeleton: quad k-split, DPP
// butterfly, chunked log2e-prescaled Gx prefetch, one lgkm-only barrier/step.
// ---------------------------------------------------------------------------

typedef _Float16 half2_t __attribute__((ext_vector_type(2)));
typedef _Float16 half4_t __attribute__((ext_vector_type(4)));
typedef _Float16 half8 __attribute__((ext_vector_type(8)));
typedef float float4_t __attribute__((ext_vector_type(4)));

#define LOG2E 1.44269504f

__device__ __forceinline__ float fast_rcp(float x) { return __builtin_amdgcn_rcpf(x); }
__device__ __forceinline__ float exp2b(float x) { return __builtin_amdgcn_exp2f(x); }

// quad butterfly on the VALU: DPP quad_perm, no LDS pipe.
__device__ __forceinline__ float qadd_xor1(float x) {
  return x + __int_as_float(__builtin_amdgcn_update_dpp(
                 0, __float_as_int(x), 0xB1, 0xF, 0xF, true));
}
__device__ __forceinline__ float qadd_xor2(float x) {
  return x + __int_as_float(__builtin_amdgcn_update_dpp(
                 0, __float_as_int(x), 0x4E, 0xF, 0xF, true));
}

// LDS-visibility-only barrier: no vmcnt drain (global stores/loads in flight).
__device__ __forceinline__ void lds_barrier() {
  asm volatile("s_waitcnt lgkmcnt(0)\n\ts_barrier" ::: "memory");
}

// fma_mix: f32 <- f16*f16 + f32 at full f32 rate (backend fuses cvt+fma).
__device__ __forceinline__ float fmix(_Float16 a, _Float16 b, float c) {
  return __builtin_fmaf((float)a, (float)b, c);
}

// Gx layout (halfs): ((br*128 + (s>>4))*512 + j*4 + g)*16 + (s&15)
// per (chunk, lane): contiguous 16-step record of gate g's preact, PRE-SCALED
// by log2e.

// ---------------------------------------------------------------------------
// K1: BN1 over branch slice [128,16,3]; writes xbn[br][s=t*128+b][d].
// ---------------------------------------------------------------------------
__global__ __launch_bounds__(128) void bn1_kernel(const float* __restrict__ x,
                                                  const float* __restrict__ g1,
                                                  const float* __restrict__ b1,
                                                  float* __restrict__ xbn) {
  const int br = blockIdx.x >> 4;
  const int t  = blockIdx.x & 15;
  const int b  = threadIdx.x;
  const float* px = x + (b * 48 + br * 16 + t) * 3;
  const float v0 = px[0], v1 = px[1], v2 = px[2];
  float s  = v0 + v1 + v2;
  float ss = v0 * v0 + v1 * v1 + v2 * v2;
  for (int off = 32; off; off >>= 1) {
    s  += __shfl_down(s, off);
    ss += __shfl_down(ss, off);
  }
  __shared__ float red[4];
  if ((threadIdx.x & 63) == 0) {
    red[(threadIdx.x >> 6) * 2]     = s;
    red[(threadIdx.x >> 6) * 2 + 1] = ss;
  }
  __syncthreads();
  const float S = red[0] + red[2], SS = red[1] + red[3];
  const float mean = S * (1.0f / 384.0f);
  const float var  = SS * (1.0f / 384.0f) - mean * mean;
  const float rstd = rsqrtf(var + 1e-5f);
  const float a  = g1[t] * rstd;
  const float sh = b1[t] - mean * a;
  float* dst = xbn + br * 6144 + (t * 128 + b) * 3;
  dst[0] = v0 * a + sh;
  dst[1] = v1 * a + sh;
  dst[2] = v2 * a + sh;
}

// ---------------------------------------------------------------------------
// K1b: G1x = (Wih1 @ xbn + bih1 + bhh1) * log2e, chunked layout.
// ---------------------------------------------------------------------------
__global__ __launch_bounds__(256) void g1x_kernel(const float* __restrict__ xbn,
                                                  const float* __restrict__ Wih1,
                                                  const float* __restrict__ bih1,
                                                  const float* __restrict__ bhh1,
                                                  _Float16* __restrict__ G1x) {
  const int br = blockIdx.x >> 10;
  const int sp = blockIdx.x & 1023;
  const int s  = sp * 2 + (threadIdx.x >> 7);
  const int j  = threadIdx.x & 127;
  const float* px = xbn + br * 6144 + s * 3;
  const float x0 = px[0], x1 = px[1], x2 = px[2];
  _Float16* base = G1x + ((size_t)(br * 128 + (s >> 4)) * 512 + j * 4) * 16 + (s & 15);
#pragma unroll
  for (int g = 0; g < 4; ++g) {
    const int row = g * 128 + j;
    const float a = bih1[row] + bhh1[row] + Wih1[row * 3] * x0 +
                    Wih1[row * 3 + 1] * x1 + Wih1[row * 3 + 2] * x2;
    base[g * 16] = (_Float16)(a * LOG2E);
  }
}

// ---------------------------------------------------------------------------
// K3a: BN2 stats per (branch, channel) over 2048 elems of H1.
// ---------------------------------------------------------------------------
__global__ __launch_bounds__(256) void bn2stats_kernel(const float* __restrict__ H1,
                                                       float* __restrict__ stats) {
  const int br = blockIdx.x >> 7;
  const int ch = blockIdx.x & 127;
  const float* base = H1 + (size_t)br * 262144 + ch * 128;
  float s = 0.f, ss = 0.f;
  for (int k = threadIdx.x; k < 2048; k += 256) {
    const int t1 = k >> 7, h = k & 127;
    const float v = base[t1 * 16384 + h];
    s += v;
    ss += v * v;
  }
  for (int off = 32; off; off >>= 1) {
    s  += __shfl_down(s, off);
    ss += __shfl_down(ss, off);
  }
  __shared__ float red[8];
  if ((threadIdx.x & 63) == 0) {
    red[(threadIdx.x >> 6) * 2]     = s;
    red[(threadIdx.x >> 6) * 2 + 1] = ss;
  }
  __syncthreads();
  if (threadIdx.x == 0) {
    const float S  = red[0] + red[2] + red[4] + red[6];
    const float SS = red[1] + red[3] + red[5] + red[7];
    const float mean = S * (1.0f / 2048.0f);
    const float var  = SS * (1.0f / 2048.0f) - mean * mean;
    stats[(br * 128 + ch) * 2]     = mean;
    stats[(br * 128 + ch) * 2 + 1] = rsqrtf(var + 1e-5f);
  }
}

// ---------------------------------------------------------------------------
// K3b: G2x = (Wih2 @ BN2(H1) + biases) * log2e, chunked layout.
// ---------------------------------------------------------------------------
__global__ __launch_bounds__(256) void g2x_kernel(
    const float* __restrict__ H1, const float* __restrict__ stats,
    const float* __restrict__ g2, const float* __restrict__ b2v,
    const float* __restrict__ Wih2, const float* __restrict__ bih2,
    const float* __restrict__ bhh2, _Float16* __restrict__ G2x) {
  const int br = blockIdx.x >> 7;
  const int t2 = blockIdx.x & 127;
  __shared__ float xh[2048];
  __shared__ float wt[64 * 129];
  const float mean = stats[(br * 128 + t2) * 2];
  const float rstd = stats[(br * 128 + t2) * 2 + 1];
  const float a  = g2[t2] * rstd;
  const float sh = b2v[t2] - mean * a;
  for (int e = threadIdx.x; e < 2048; e += 256) {
    const int b2 = e >> 7, d = e & 127;
    xh[e] = H1[(size_t)br * 262144 + (size_t)(b2 * 128 + t2) * 128 + d] * a + sh;
  }
  const int gl  = threadIdx.x & 63;
  const int b2b = (threadIdx.x >> 6) * 4;
  for (int gt = 0; gt < 8; ++gt) {
    __syncthreads();
    for (int e = threadIdx.x; e < 8192; e += 256)
      wt[(e >> 7) * 129 + (e & 127)] = Wih2[gt * 8192 + e];
    __syncthreads();
    float a0 = 0.f, a1 = 0.f, a2 = 0.f, a3 = 0.f;
    for (int d = 0; d < 128; ++d) {
      const float w = wt[gl * 129 + d];
      a0 += w * xh[(b2b + 0) * 128 + d];
      a1 += w * xh[(b2b + 1) * 128 + d];
      a2 += w * xh[(b2b + 2) * 128 + d];
      a3 += w * xh[(b2b + 3) * 128 + d];
    }
    const int g    = gt * 64 + gl;
    const int gate = g >> 7;
    const int jj   = g & 127;
    const float bb = bih2[g] + bhh2[g];
    _Float16* dst = G2x + ((size_t)(br * 128 + t2) * 512 + jj * 4 + gate) * 16 + b2b;
    *reinterpret_cast<half4_t*>(dst) =
        half4_t{(_Float16)((a0 + bb) * LOG2E), (_Float16)((a1 + bb) * LOG2E),
                (_Float16)((a2 + bb) * LOG2E), (_Float16)((a3 + bb) * LOG2E)};
  }
}

// ---------------------------------------------------------------------------
// K2/K4: the recurrence. 1 block/branch, 512 threads (8 waves, 2/SIMD).
// Lane tid: j = tid>>2, g = tid&3. Owns k-quarter [32g,32g+32) of all 4 gate
// rows of j as half2 VGPRs (log2e-prescaled, 64 regs). h_sh f16 (quarters at
// 64B offsets: 2-way bank alias = free). Per step: 4 ds_read_b128 of h;
// 128 v_fma_mix_f32 in 8 indep f32 chains; DPP quad butterfly; exp2-direct
// epilogue; g==0 writes h + output. One lgkm-only barrier per step.
// Gx: 2 half8 loads per 16-step chunk, waited one chunk later.
// ---------------------------------------------------------------------------
__global__ __launch_bounds__(512, 2) void lstm_kernel(
    const float* __restrict__ Whh, const float* __restrict__ h0s,
    const float* __restrict__ c0s, const _Float16* __restrict__ Gx,
    float* __restrict__ outp, int layer) {
  const int br  = blockIdx.x;
  const int tid = threadIdx.x;
  const int j   = tid >> 2;
  const int g   = tid & 3;

  __shared__ __align__(16) _Float16 h_sh[2][128];

  // ---- stage Whh rows q*128+j, k in [32g,32g+32), f16, pre-scaled log2e ----
  half2_t w0[16], w1[16], w2[16], w3[16];
  {
    const float4_t* W4 = (const float4_t*)Whh;
#pragma unroll
    for (int k8 = 0; k8 < 8; ++k8) {
      const float4_t v0 = W4[((0 * 128 + j) * 128 + g * 32) / 4 + k8];
      w0[2 * k8]     = half2_t{(_Float16)(v0[0] * LOG2E), (_Float16)(v0[1] * LOG2E)};
      w0[2 * k8 + 1] = half2_t{(_Float16)(v0[2] * LOG2E), (_Float16)(v0[3] * LOG2E)};
      const float4_t v1 = W4[((1 * 128 + j) * 128 + g * 32) / 4 + k8];
      w1[2 * k8]     = half2_t{(_Float16)(v1[0] * LOG2E), (_Float16)(v1[1] * LOG2E)};
      w1[2 * k8 + 1] = half2_t{(_Float16)(v1[2] * LOG2E), (_Float16)(v1[3] * LOG2E)};
      const float4_t v2 = W4[((2 * 128 + j) * 128 + g * 32) / 4 + k8];
      w2[2 * k8]     = half2_t{(_Float16)(v2[0] * LOG2E), (_Float16)(v2[1] * LOG2E)};
      w2[2 * k8 + 1] = half2_t{(_Float16)(v2[2] * LOG2E), (_Float16)(v2[3] * LOG2E)};
      const float4_t v3 = W4[((3 * 128 + j) * 128 + g * 32) / 4 + k8];
      w3[2 * k8]     = half2_t{(_Float16)(v3[0] * LOG2E), (_Float16)(v3[1] * LOG2E)};
      w3[2 * k8 + 1] = half2_t{(_Float16)(v3[2] * LOG2E), (_Float16)(v3[3] * LOG2E)};
    }
  }

  const int slot = 2 * br + layer;
  float c = c0s[slot * 128 + j];  // quad lanes hold identical c
  if (tid < 128) h_sh[0][tid] = (_Float16)h0s[slot * 128 + tid];

  const bool gm0 = (g == 0), gm1 = (g == 1), gm2 = (g == 2), gm3 = (g == 3);

  // Gx chunk stream: record = 16 halfs at ((br*128+ch)*512 + tid)*16
  const half8* gq = (const half8*)Gx;
  size_t rec = ((size_t)(br * 128) * 512 + tid) * 2;  // in half8 units
  half8 curA = gq[rec], curB = gq[rec + 1];
  float* op = outp + (size_t)br * 262144 + j;

  __syncthreads();  // once; full drain fine

  for (int chk = 0; chk < 128; ++chk) {
    const int chn = (chk < 127) ? chk + 1 : 127;
    const size_t nrec = ((size_t)(br * 128 + chn) * 512 + tid) * 2;
    const half8 nA = gq[nrec], nB = gq[nrec + 1];  // waited at chunk end

#pragma unroll
    for (int u = 0; u < 16; ++u) {
      // h read: this lane's k-quarter (32 halfs = 4 x b128)
      const half8* hb = (const half8*)(&h_sh[u & 1][g * 32]);
      half8 hr0 = hb[0], hr1 = hb[1], hr2 = hb[2], hr3 = hb[3];
      half2_t hh[16];
      *(half8*)&hh[0]  = hr0;
      *(half8*)&hh[4]  = hr1;
      *(half8*)&hh[8]  = hr2;
      *(half8*)&hh[12] = hr3;

      const float pre = (float)((u < 8) ? curA[u] : curB[u - 8]);

      // 8 independent f32 chains of v_fma_mix_f32 (2 per gate)
      float a0a = 0.f, a0b = 0.f, a1a = 0.f, a1b = 0.f;
      float a2a = 0.f, a2b = 0.f, a3a = 0.f, a3b = 0.f;
#pragma unroll
      for (int k = 0; k < 8; ++k) {
        a0a = fmix(w0[k][0], hh[k][0], a0a);
        a0a = fmix(w0[k][1], hh[k][1], a0a);
        a0b = fmix(w0[8 + k][0], hh[8 + k][0], a0b);
        a0b = fmix(w0[8 + k][1], hh[8 + k][1], a0b);
        a1a = fmix(w1[k][0], hh[k][0], a1a);
        a1a = fmix(w1[k][1], hh[k][1], a1a);
        a1b = fmix(w1[8 + k][0], hh[8 + k][0], a1b);
        a1b = fmix(w1[8 + k][1], hh[8 + k][1], a1b);
        a2a = fmix(w2[k][0], hh[k][0], a2a);
        a2a = fmix(w2[k][1], hh[k][1], a2a);
        a2b = fmix(w2[8 + k][0], hh[8 + k][0], a2b);
        a2b = fmix(w2[8 + k][1], hh[8 + k][1], a2b);
        a3a = fmix(w3[k][0], hh[k][0], a3a);
        a3a = fmix(w3[k][1], hh[k][1], a3a);
        a3b = fmix(w3[8 + k][0], hh[8 + k][0], a3b);
        a3b = fmix(w3[8 + k][1], hh[8 + k][1], a3b);
      }
      float a0 = (gm0 ? pre : 0.f) + (a0a + a0b);
      float a1 = (gm1 ? pre : 0.f) + (a1a + a1b);
      float a2 = (gm2 ? pre : 0.f) + (a2a + a2b);
      float a3 = (gm3 ? pre : 0.f) + (a3a + a3b);

      // quad butterfly on the VALU (DPP): full gate sums in every lane
      a0 = qadd_xor1(a0);
      a1 = qadd_xor1(a1);
      a2 = qadd_xor1(a2);
      a3 = qadd_xor1(a3);
      a0 = qadd_xor2(a0);
      a1 = qadd_xor2(a1);
      a2 = qadd_xor2(a2);
      a3 = qadd_xor2(a3);

      // a* are log2e-scaled preacts: feed exp2 directly
      const float iv = fast_rcp(1.0f + exp2b(-a0));
      const float fv = fast_rcp(1.0f + exp2b(-a1));
      const float gv = 1.0f - 2.0f * fast_rcp(1.0f + exp2b(a2 + a2));
      const float ov = fast_rcp(1.0f + exp2b(-a3));
      c = fv * c + iv * gv;
      const float t  = 1.0f - 2.0f * fast_rcp(1.0f + exp2b(c * 2.88539008f));
      const float hv = ov * t;

      if (g == 0) {
        h_sh[(u + 1) & 1][j] = (_Float16)hv;
        *op = hv;
      }
      op += 128;
      lds_barrier();  // h broadcast; lgkm-only
    }

    curA = nA;  // vmcnt wait lands here, one full chunk after issue
    curB = nB;
  }
}

// ---------------------------------------------------------------------------
// Workspace layout (floats):
//   xbn   [3][2048][3]            @ 0        (18432)
//   H1    [3][2048][128]          @ 18432    (786432)
//   stats [3][128][2]             @ 804864   (768)
//   G1x   chunked f16             @ 805632   (1572864 floats)
//   G2x   chunked f16             @ 2378496  (1572864 floats)   total ~15.8 MB
// ---------------------------------------------------------------------------
extern "C" void kernel_launch(void* const* d_in, const int* in_sizes, int n_in,
                              void* d_out, int out_size, void* d_ws, size_t ws_size,
                              hipStream_t stream) {
  const float* x    = (const float*)d_in[0];
  const float* g1   = (const float*)d_in[1];
  const float* b1   = (const float*)d_in[2];
  const float* Wih1 = (const float*)d_in[3];
  const float* Whh1 = (const float*)d_in[4];
  const float* bih1 = (const float*)d_in[5];
  const float* bhh1 = (const float*)d_in[6];
  const float* g2   = (const float*)d_in[7];
  const float* b2   = (const float*)d_in[8];
  const float* Wih2 = (const float*)d_in[9];
  const float* Whh2 = (const float*)d_in[10];
  const float* bih2 = (const float*)d_in[11];
  const float* bhh2 = (const float*)d_in[12];
  const float* h0s  = (const float*)d_in[13];
  const float* c0s  = (const float*)d_in[14];

  float* ws   = (float*)d_ws;
  float* xbn  = ws;
  float* H1b  = ws + 18432;
  float* st   = ws + 18432 + 786432;
  _Float16* G1xb = (_Float16*)(ws + 805632);
  _Float16* G2xb = (_Float16*)(ws + 2378496);
  float* outp = (float*)d_out;

  bn1_kernel<<<48, 128, 0, stream>>>(x, g1, b1, xbn);
  g1x_kernel<<<3072, 256, 0, stream>>>(xbn, Wih1, bih1, bhh1, G1xb);
  lstm_kernel<<<3, 512, 0, stream>>>(Whh1, h0s, c0s, G1xb, H1b, 0);
  bn2stats_kernel<<<384, 256, 0, stream>>>(H1b, st);
  g2x_kernel<<<384, 256, 0, stream>>>(H1b, st, g2, b2, Wih2, bih2, bhh2, G2xb);
  lstm_kernel<<<3, 512, 0, stream>>>(Whh2, h0s, c0s, G2xb, outp, 1);
}

// Round 13
// 1856.499 us; speedup vs baseline: 1.7510x; 1.7510x over previous
//
#include <hip/hip_runtime.h>

// ---------------------------------------------------------------------------
// TypeNet: 3 branches x (BN1 -> flattened LSTM (2048 steps) -> BN2 -> LSTM (2048 steps))
// H = 128, gates = 512. Round 13: matvec back on the MATRIX pipe (fixed ~620
// cyc/SIMD, separate from VALU; MFMA reads AGPRs natively so R11's spill
// penalty doesn't apply), with the VALU epilogue cut to ~35 instr/lane:
// lane l15 = rr*4+gate owns one (j,gate) cell -> 15-cndmask select, ONE
// unified activation act = 1 - B*rcp(1+exp2(s*a)) (branchless sigm/tanh,
// 2 trans), 4 quad_perm broadcasts collect iv/fv/gv/ov, redundant c per
// 4-lane group. Chunked log2e-prescaled Gx prefetch (R8), one lgkm-only
// barrier per step. f16 VALU ops (6-8cyc each: R8/R9/R12) fully avoided.
// ---------------------------------------------------------------------------

typedef _Float16 half4_t __attribute__((ext_vector_type(4)));
typedef _Float16 half8 __attribute__((ext_vector_type(8)));
typedef float float4_t __attribute__((ext_vector_type(4)));

#define LOG2E 1.44269504f

__device__ __forceinline__ float fast_rcp(float x) { return __builtin_amdgcn_rcpf(x); }
__device__ __forceinline__ float exp2b(float x) { return __builtin_amdgcn_exp2f(x); }

// DPP quad broadcast: every lane of each aligned 4-lane group gets the value
// of the group's lane PAT (0x00/0x55/0xAA/0xFF for lanes 0/1/2/3).
#define QBCAST(x, pat)                                                        \
  __int_as_float(__builtin_amdgcn_update_dpp(0, __float_as_int(x), (pat),     \
                                             0xF, 0xF, true))

// LDS-visibility-only barrier: no vmcnt drain (global stores/loads in flight).
__device__ __forceinline__ void lds_barrier() {
  asm volatile("s_waitcnt lgkmcnt(0)\n\ts_barrier" ::: "memory");
}

// Gx record index for (j, gate): lane mapping of the lstm kernel.
// ridx = (j>>4)*64 + ((j>>2)&3)*16 + (j&3)*4 + gate
__host__ __device__ __forceinline__ int ridx0_of(int j) {
  return (j >> 4) * 64 + ((j >> 2) & 3) * 16 + (j & 3) * 4;
}

// ---------------------------------------------------------------------------
// K1: BN1 over branch slice [128,16,3]; writes xbn[br][s=t*128+b][d].
// ---------------------------------------------------------------------------
__global__ __launch_bounds__(128) void bn1_kernel(const float* __restrict__ x,
                                                  const float* __restrict__ g1,
                                                  const float* __restrict__ b1,
                                                  float* __restrict__ xbn) {
  const int br = blockIdx.x >> 4;
  const int t  = blockIdx.x & 15;
  const int b  = threadIdx.x;
  const float* px = x + (b * 48 + br * 16 + t) * 3;
  const float v0 = px[0], v1 = px[1], v2 = px[2];
  float s  = v0 + v1 + v2;
  float ss = v0 * v0 + v1 * v1 + v2 * v2;
  for (int off = 32; off; off >>= 1) {
    s  += __shfl_down(s, off);
    ss += __shfl_down(ss, off);
  }
  __shared__ float red[4];
  if ((threadIdx.x & 63) == 0) {
    red[(threadIdx.x >> 6) * 2]     = s;
    red[(threadIdx.x >> 6) * 2 + 1] = ss;
  }
  __syncthreads();
  const float S = red[0] + red[2], SS = red[1] + red[3];
  const float mean = S * (1.0f / 384.0f);
  const float var  = SS * (1.0f / 384.0f) - mean * mean;
  const float rstd = rsqrtf(var + 1e-5f);
  const float a  = g1[t] * rstd;
  const float sh = b1[t] - mean * a;
  float* dst = xbn + br * 6144 + (t * 128 + b) * 3;
  dst[0] = v0 * a + sh;
  dst[1] = v1 * a + sh;
  dst[2] = v2 * a + sh;
}

// ---------------------------------------------------------------------------
// K1b: G1x = (Wih1 @ xbn + bih1 + bhh1) * log2e, chunked layout w/ ridx map.
// ---------------------------------------------------------------------------
__global__ __launch_bounds__(256) void g1x_kernel(const float* __restrict__ xbn,
                                                  const float* __restrict__ Wih1,
                                                  const float* __restrict__ bih1,
                                                  const float* __restrict__ bhh1,
                                                  _Float16* __restrict__ G1x) {
  const int br = blockIdx.x >> 10;
  const int sp = blockIdx.x & 1023;
  const int s  = sp * 2 + (threadIdx.x >> 7);
  const int j  = threadIdx.x & 127;
  const float* px = xbn + br * 6144 + s * 3;
  const float x0 = px[0], x1 = px[1], x2 = px[2];
  _Float16* base =
      G1x + ((size_t)(br * 128 + (s >> 4)) * 512 + ridx0_of(j)) * 16 + (s & 15);
#pragma unroll
  for (int g = 0; g < 4; ++g) {
    const int row = g * 128 + j;
    const float a = bih1[row] + bhh1[row] + Wih1[row * 3] * x0 +
                    Wih1[row * 3 + 1] * x1 + Wih1[row * 3 + 2] * x2;
    base[g * 16] = (_Float16)(a * LOG2E);
  }
}

// ---------------------------------------------------------------------------
// K3a: BN2 stats per (branch, channel) over 2048 elems of H1.
// ---------------------------------------------------------------------------
__global__ __launch_bounds__(256) void bn2stats_kernel(const float* __restrict__ H1,
                                                       float* __restrict__ stats) {
  const int br = blockIdx.x >> 7;
  const int ch = blockIdx.x & 127;
  const float* base = H1 + (size_t)br * 262144 + ch * 128;
  float s = 0.f, ss = 0.f;
  for (int k = threadIdx.x; k < 2048; k += 256) {
    const int t1 = k >> 7, h = k & 127;
    const float v = base[t1 * 16384 + h];
    s += v;
    ss += v * v;
  }
  for (int off = 32; off; off >>= 1) {
    s  += __shfl_down(s, off);
    ss += __shfl_down(ss, off);
  }
  __shared__ float red[8];
  if ((threadIdx.x & 63) == 0) {
    red[(threadIdx.x >> 6) * 2]     = s;
    red[(threadIdx.x >> 6) * 2 + 1] = ss;
  }
  __syncthreads();
  if (threadIdx.x == 0) {
    const float S  = red[0] + red[2] + red[4] + red[6];
    const float SS = red[1] + red[3] + red[5] + red[7];
    const float mean = S * (1.0f / 2048.0f);
    const float var  = SS * (1.0f / 2048.0f) - mean * mean;
    stats[(br * 128 + ch) * 2]     = mean;
    stats[(br * 128 + ch) * 2 + 1] = rsqrtf(var + 1e-5f);
  }
}

// ---------------------------------------------------------------------------
// K3b: G2x = (Wih2 @ BN2(H1) + biases) * log2e, chunked layout w/ ridx map.
// ---------------------------------------------------------------------------
__global__ __launch_bounds__(256) void g2x_kernel(
    const float* __restrict__ H1, const float* __restrict__ stats,
    const float* __restrict__ g2, const float* __restrict__ b2v,
    const float* __restrict__ Wih2, const float* __restrict__ bih2,
    const float* __restrict__ bhh2, _Float16* __restrict__ G2x) {
  const int br = blockIdx.x >> 7;
  const int t2 = blockIdx.x & 127;
  __shared__ float xh[2048];
  __shared__ float wt[64 * 129];
  const float mean = stats[(br * 128 + t2) * 2];
  const float rstd = stats[(br * 128 + t2) * 2 + 1];
  const float a  = g2[t2] * rstd;
  const float sh = b2v[t2] - mean * a;
  for (int e = threadIdx.x; e < 2048; e += 256) {
    const int b2 = e >> 7, d = e & 127;
    xh[e] = H1[(size_t)br * 262144 + (size_t)(b2 * 128 + t2) * 128 + d] * a + sh;
  }
  const int gl  = threadIdx.x & 63;
  const int b2b = (threadIdx.x >> 6) * 4;
  for (int gt = 0; gt < 8; ++gt) {
    __syncthreads();
    for (int e = threadIdx.x; e < 8192; e += 256)
      wt[(e >> 7) * 129 + (e & 127)] = Wih2[gt * 8192 + e];
    __syncthreads();
    float a0 = 0.f, a1 = 0.f, a2 = 0.f, a3 = 0.f;
    for (int d = 0; d < 128; ++d) {
      const float w = wt[gl * 129 + d];
      a0 += w * xh[(b2b + 0) * 128 + d];
      a1 += w * xh[(b2b + 1) * 128 + d];
      a2 += w * xh[(b2b + 2) * 128 + d];
      a3 += w * xh[(b2b + 3) * 128 + d];
    }
    const int g    = gt * 64 + gl;
    const int gate = g >> 7;
    const int jj   = g & 127;
    const int ri   = ridx0_of(jj) + gate;
    const float bb = bih2[g] + bhh2[g];
    _Float16* dst = G2x + ((size_t)(br * 128 + t2) * 512 + ri) * 16 + b2b;
    *reinterpret_cast<half4_t*>(dst) =
        half4_t{(_Float16)((a0 + bb) * LOG2E), (_Float16)((a1 + bb) * LOG2E),
                (_Float16)((a2 + bb) * LOG2E), (_Float16)((a3 + bb) * LOG2E)};
  }
}

// ---------------------------------------------------------------------------
// K2/K4: the recurrence. 1 block/branch, 512 threads (8 waves, 2/SIMD).
// MFMA 16x16x32_f16: wave w owns one 16-row m-tile per gate (rows
// g*128 + w*16 + l15), 16 MFMAs/wave/step on the matrix pipe. All 16 D
// columns identical. Epilogue lane l15 = rr*4 + gate: owns cell
// (j = w*16 + quad*4 + rr, gate) -> 15 cndmask select + pre add + unified
// activation + 4 quad_perm collects + c/tanh(c). gate==0 lanes write h+out.
// Gx: 2 half8 loads per 16-step chunk, waited one chunk later. One
// lgkm-only barrier per step.
// ---------------------------------------------------------------------------
__global__ __launch_bounds__(512, 1) void lstm_kernel(
    const float* __restrict__ Whh, const float* __restrict__ h0s,
    const float* __restrict__ c0s, const _Float16* __restrict__ Gx,
    float* __restrict__ outp, int layer) {
  const int br   = blockIdx.x;
  const int tid  = threadIdx.x;
  const int wave = tid >> 6;
  const int lane = tid & 63;
  const int quad = lane >> 4;
  const int l15  = lane & 15;
  const int gate = l15 & 3;
  const int rr   = l15 >> 2;
  const int j    = wave * 16 + quad * 4 + rr;  // this lane's cell row
  const bool rb0 = (rr & 1) != 0;
  const bool rb1 = (rr & 2) != 0;
  const bool gb0 = (gate & 1) != 0;
  const bool gb1 = (gate & 2) != 0;
  // unified activation constants: sigm (gates i,f,o): s=1,B=1; tanh (g): s=2,B=2
  const float sc = (gate == 2) ? 2.0f : 1.0f;
  const float Bc = (gate == 2) ? 2.0f : 1.0f;

  __shared__ __align__(16) _Float16 h_sh[2][128];

  // ---- preload Whh as f16 A-fragments (log2e-prescaled): 1 m-tile/gate ----
  half8 afrag[4][4];
#pragma unroll
  for (int g = 0; g < 4; ++g) {
    const int row = g * 128 + wave * 16 + l15;
#pragma unroll
    for (int kt = 0; kt < 4; ++kt) {
      const float* src = Whh + row * 128 + kt * 32 + quad * 8;
      half8 f;
#pragma unroll
      for (int jj = 0; jj < 8; ++jj) f[jj] = (_Float16)(src[jj] * LOG2E);
      afrag[g][kt] = f;
    }
  }

  const int slot = 2 * br + layer;
  float c = c0s[slot * 128 + j];  // 4 gate-lanes per j hold identical c
  if (tid < 128) h_sh[0][tid] = (_Float16)h0s[slot * 128 + tid];

  // Gx chunk stream: record = 16 halfs at ((br*128+ch)*512 + tid)*16
  const half8* gq = (const half8*)Gx;
  half8 curA = gq[((size_t)(br * 128) * 512 + tid) * 2];
  half8 curB = gq[((size_t)(br * 128) * 512 + tid) * 2 + 1];
  float* op = outp + (size_t)br * 262144 + j;

  const float4_t zacc = {0.f, 0.f, 0.f, 0.f};
  __syncthreads();  // once; full drain fine

  for (int chk = 0; chk < 128; ++chk) {
    const int chn = (chk < 127) ? chk + 1 : 127;
    const size_t nrec = ((size_t)(br * 128 + chn) * 512 + tid) * 2;
    const half8 nA = gq[nrec], nB = gq[nrec + 1];  // waited at chunk end

#pragma unroll
    for (int u = 0; u < 16; ++u) {
      // B fragments: every lane supplies h[k] -> every D column is the matvec
      const _Float16* hcur = h_sh[u & 1];
      half8 bfrag[4];
#pragma unroll
      for (int kt = 0; kt < 4; ++kt)
        bfrag[kt] = *reinterpret_cast<const half8*>(&hcur[kt * 32 + quad * 8]);

      const float pre = (float)((u < 8) ? curA[u] : curB[u - 8]);

      // 4 independent MFMA chains (one per gate), zero-C first MFMA
      float4_t acc[4];
#pragma unroll
      for (int g = 0; g < 4; ++g)
        acc[g] = __builtin_amdgcn_mfma_f32_16x16x32_f16(afrag[g][0], bfrag[0],
                                                        zacc, 0, 0, 0);
#pragma unroll
      for (int kt = 1; kt < 4; ++kt)
#pragma unroll
        for (int g = 0; g < 4; ++g)
          acc[g] = __builtin_amdgcn_mfma_f32_16x16x32_f16(afrag[g][kt],
                                                          bfrag[kt], acc[g], 0, 0, 0);

      // select element rr of each gate's acc (12 cndmask), then gate (3)
      float e0, e1, e2, e3;
      {
        float x, y;
        x = rb0 ? acc[0][1] : acc[0][0]; y = rb0 ? acc[0][3] : acc[0][2];
        e0 = rb1 ? y : x;
        x = rb0 ? acc[1][1] : acc[1][0]; y = rb0 ? acc[1][3] : acc[1][2];
        e1 = rb1 ? y : x;
        x = rb0 ? acc[2][1] : acc[2][0]; y = rb0 ? acc[2][3] : acc[2][2];
        e2 = rb1 ? y : x;
        x = rb0 ? acc[3][1] : acc[3][0]; y = rb0 ? acc[3][3] : acc[3][2];
        e3 = rb1 ? y : x;
      }
      const float eA = gb0 ? e1 : e0;
      const float eB = gb0 ? e3 : e2;
      const float a  = (gb1 ? eB : eA) + pre;  // log2e-scaled preact, own gate

      // unified activation: sigm or tanh via 1 - B*rcp(1 + exp2(s*a))
      const float act = __builtin_fmaf(-Bc, fast_rcp(1.0f + exp2b(sc * a)), 1.0f);

      // collect the 4 gates' activations across the aligned 4-lane group
      const float iv = QBCAST(act, 0x00);
      const float fv = QBCAST(act, 0x55);
      const float gv = QBCAST(act, 0xAA);
      const float ov = QBCAST(act, 0xFF);

      c = fv * c + iv * gv;
      const float t  = __builtin_fmaf(
          -2.0f, fast_rcp(1.0f + exp2b(c * 2.88539008f)), 1.0f);
      const float hv = ov * t;

      if (gate == 0) {
        h_sh[(u + 1) & 1][j] = (_Float16)hv;
        *op = hv;
      }
      op += 128;
      lds_barrier();  // h broadcast; lgkm-only
    }

    curA = nA;  // vmcnt wait lands here, one full chunk after issue
    curB = nB;
  }
}

// ---------------------------------------------------------------------------
// Workspace layout (floats):
//   xbn   [3][2048][3]            @ 0        (18432)
//   H1    [3][2048][128]          @ 18432    (786432)
//   stats [3][128][2]             @ 804864   (768)
//   G1x   chunked f16             @ 805632   (1572864 floats)
//   G2x   chunked f16             @ 2378496  (1572864 floats)   total ~15.8 MB
// ---------------------------------------------------------------------------
extern "C" void kernel_launch(void* const* d_in, const int* in_sizes, int n_in,
                              void* d_out, int out_size, void* d_ws, size_t ws_size,
                              hipStream_t stream) {
  const float* x    = (const float*)d_in[0];
  const float* g1   = (const float*)d_in[1];
  const float* b1   = (const float*)d_in[2];
  const float* Wih1 = (const float*)d_in[3];
  const float* Whh1 = (const float*)d_in[4];
  const float* bih1 = (const float*)d_in[5];
  const float* bhh1 = (const float*)d_in[6];
  const float* g2   = (const float*)d_in[7];
  const float* b2   = (const float*)d_in[8];
  const float* Wih2 = (const float*)d_in[9];
  const float* Whh2 = (const float*)d_in[10];
  const float* bih2 = (const float*)d_in[11];
  const float* bhh2 = (const float*)d_in[12];
  const float* h0s  = (const float*)d_in[13];
  const float* c0s  = (const float*)d_in[14];

  float* ws   = (float*)d_ws;
  float* xbn  = ws;
  float* H1b  = ws + 18432;
  float* st   = ws + 18432 + 786432;
  _Float16* G1xb = (_Float16*)(ws + 805632);
  _Float16* G2xb = (_Float16*)(ws + 2378496);
  float* outp = (float*)d_out;

  bn1_kernel<<<48, 128, 0, stream>>>(x, g1, b1, xbn);
  g1x_kernel<<<3072, 256, 0, stream>>>(xbn, Wih1, bih1, bhh1, G1xb);
  lstm_kernel<<<3, 512, 0, stream>>>(Whh1, h0s, c0s, G1xb, H1b, 0);
  bn2stats_kernel<<<384, 256, 0, stream>>>(H1b, st);
  g2x_kernel<<<384, 256, 0, stream>>>(H1b, st, g2, b2, Wih2, bih2, bhh2, G2xb);
  lstm_kernel<<<3, 512, 0, stream>>>(Whh2, h0s, c0s, G2xb, outp, 1);
}